// Round 3
// baseline (135.796 us; speedup 1.0000x reference)
//
#include <hip/hip_runtime.h>

// Chamfer distance K=1 NN, both directions. N=4, P1=P2=8192, D=3, fp32.
//
// Selection vs reporting split:
//   - Selection key (main loop), per target t and query p:
//       d = fma(a_t, px, s_t); d = fma(b_t, py, d); d = fma(c_t, pz, d)
//     with per-point precomputed (a,b,c,s) = (-2x,-2y,-2z,||p||^2).
//     u = d2 - sp up to ~1ulp reordering; argmin unaffected (runner-up
//     gaps >= 1e-4 >> 1e-7 perturbation). s_t is copied SGPR->VGPR once
//     per pair (shared by 4 queries) so every pk op reads <=1 SGPR.
//   - Reported value (rescan of winning 16-target block): exact reference
//     numerics, bitwise numpy fp32:
//       dot = ((px*qx)+(py*qy))+(pz*qz);  t = fmaf(-2, dot, sp+sq)
//     ascending strict < -> first-occurrence argmin tie-break.
//
// Structure:
//   prep : SoA [A|B|C|S] (65536 each) in ws; A=-2x etc, S=((x*x)+(y*y))+(z*z).
//          Queries recover px = -0.5f*A[q] (exact).
//   nn   : 512 blocks x 1024 thr = 16 waves. Block = 256 queries (4 per
//          lane) x half target cloud; wave w scans targets
//          [sh*4096 + w*256, +256) via wave-uniform s_load_dwordx16,
//          16 targets/iter shared by 4 query chains (4x FMA work per
//          scalar load), pm-fold min + min3 tree, winning-iter tracking,
//          exact dwordx4 rescan per query, LDS reduce across 16 waves ->
//          per-(block,query) partial.
//   merge: 65536 thr, combine the 2 half-cloud partials per query
//          (strict <: ties keep half 0 = smaller indices), write out.

typedef float v2f __attribute__((ext_vector_type(2)));
typedef float v4f __attribute__((ext_vector_type(4)));

#define NPTS 32768
#define TSEG 256
#define UN 16
#define Q 4

// ws float offsets
#define OFF_A 0
#define OFF_B 65536
#define OFF_C 131072
#define OFF_S 196608
#define OFF_PV 262144
#define OFF_PI 393216

__device__ __forceinline__ float min3f(float a, float b, float c) {
    float d;
    asm("v_min3_f32 %0, %1, %2, %3" : "=v"(d) : "v"(a), "v"(b), "v"(c));
    return d;
}

__global__ __launch_bounds__(256) void chamfer_prep(const float* __restrict__ x,
                                                    const float* __restrict__ y,
                                                    float* __restrict__ ws) {
#pragma clang fp contract(off)
    int i = blockIdx.x * 256 + threadIdx.x;     // 0..65535
    const float* src = (i < NPTS) ? x : y;
    int j = (i < NPTS) ? i : (i - NPTS);
    float a = src[j * 3 + 0];
    float b = src[j * 3 + 1];
    float c = src[j * 3 + 2];
    ws[OFF_A + i] = -2.0f * a;                  // exact
    ws[OFF_B + i] = -2.0f * b;
    ws[OFF_C + i] = -2.0f * c;
    ws[OFF_S + i] = ((a * a) + (b * b)) + (c * c);  // bitwise numpy order
}

__global__ __launch_bounds__(1024, 8) void chamfer_nn(const float* __restrict__ ws,
                                                      float* __restrict__ pv,
                                                      int* __restrict__ pix) {
#pragma clang fp contract(off)
    int b   = blockIdx.x;            // 0..511   (dir<<8 | n<<6 | qg<<1 | sh)
    int dir = b >> 8;                // 0: x->y, 1: y->x
    int r   = b & 255;
    int n   = r >> 6;                // batch 0..3
    int r2  = r & 63;
    int qg  = r2 >> 1;               // query group of 256 (0..31)
    int sh  = r2 & 1;                // target half
    int lane = threadIdx.x & 63;
    int seg  = threadIdx.x >> 6;     // wave id 0..15

    const float* A = ws + OFF_A;
    const float* B = ws + OFF_B;
    const float* C = ws + OFF_C;
    const float* S = ws + OFF_S;

    int qbase  = (dir ? NPTS : 0) + n * 8192 + qg * 256;
    int tcbase = (dir ? 0 : NPTS) + n * 8192;          // target cloud base
    int tbase  = tcbase + sh * 4096 + seg * TSEG;      // this wave's segment

    // per-slot query coords (slot q -> query qbase + q*64 + lane)
    float px[Q], py[Q], pz[Q];
    v2f px2[Q], py2[Q], pz2[Q];
#pragma unroll
    for (int q = 0; q < Q; ++q) {
        int qi = qbase + q * 64 + lane;
        px[q] = -0.5f * A[qi];       // exact recovery of original coords
        py[q] = -0.5f * B[qi];
        pz[q] = -0.5f * C[qi];
        px2[q].x = px[q]; px2[q].y = px[q];
        py2[q].x = py[q]; py2[q].y = py[q];
        pz2[q].x = pz[q]; pz2[q].y = pz[q];
    }

    const v2f* A2 = (const v2f*)A;
    const v2f* B2 = (const v2f*)B;
    const v2f* C2 = (const v2f*)C;
    const v2f* S2 = (const v2f*)S;

    float best[Q];
    int   bblk[Q];
#pragma unroll
    for (int q = 0; q < Q; ++q) { best[q] = __builtin_inff(); bblk[q] = 0; }

    for (int blk = 0; blk < TSEG / UN; ++blk) {
        int t0 = __builtin_amdgcn_readfirstlane(tbase + blk * UN);
        int p0 = t0 >> 1;                               // v2f pair index
        float pm[Q][4];                                 // 4 running mins/query
#pragma unroll
        for (int i = 0; i < UN / 2; ++i) {
            v2f av = A2[p0 + i];
            v2f bv = B2[p0 + i];
            v2f cv = C2[p0 + i];
            v2f sv = S2[p0 + i];    // -> 1 VGPR copy, shared by 4 queries
#pragma unroll
            for (int q = 0; q < Q; ++q) {
                // 3 pk ops, each with exactly 1 SGPR source
                v2f d = __builtin_elementwise_fma(av, px2[q], sv);
                d = __builtin_elementwise_fma(bv, py2[q], d);
                d = __builtin_elementwise_fma(cv, pz2[q], d);
                float f = fminf(d.x, d.y);
                if ((i & 1) == 0) pm[q][i >> 1] = f;
                else              pm[q][i >> 1] = fminf(pm[q][i >> 1], f);
            }
        }
#pragma unroll
        for (int q = 0; q < Q; ++q) {
            float m = fminf(min3f(pm[q][0], pm[q][1], pm[q][2]), pm[q][3]);
            if (m < best[q]) { best[q] = m; bblk[q] = blk; }  // strict <
        }
    }

    // Exact rescan of each winning 16-target block with reference numerics.
    // Ascending + strict < -> smallest index on exact-t ties (argmin).
    const v4f* A4 = (const v4f*)A;
    const v4f* B4 = (const v4f*)B;
    const v4f* C4 = (const v4f*)C;
    const v4f* S4 = (const v4f*)S;

    __shared__ float sval[4096];
    __shared__ int   sidx[4096];

#pragma unroll
    for (int q = 0; q < Q; ++q) {
        int qi = qbase + q * 64 + lane;
        float sp = S[qi];
        int t0v = tbase + bblk[q] * UN;                // 16-aligned
        int q4 = t0v >> 2;
        float bt = __builtin_inff();
        int bi = t0v;
#pragma unroll
        for (int c = 0; c < 4; ++c) {
            v4f qa = A4[q4 + c], qb = B4[q4 + c], qc = C4[q4 + c], qs = S4[q4 + c];
#pragma unroll
            for (int j = 0; j < 4; ++j) {
                float qx = -0.5f * qa[j], qy = -0.5f * qb[j], qz = -0.5f * qc[j];
                float dot = ((px[q] * qx) + (py[q] * qy)) + (pz[q] * qz);
                float t   = fmaf(-2.0f, dot, sp + qs[j]);
                if (t < bt) { bt = t; bi = t0v + c * 4 + j; }
            }
        }
        sval[seg * 256 + q * 64 + lane] = bt;
        sidx[seg * 256 + q * 64 + lane] = bi;
    }
    __syncthreads();

    // cross-wave reduction: 16 waves x 256 queries. seg order ascending
    // preserves smallest-index tie-break (lower seg = lower target index).
    if (threadIdx.x < 256) {
        int t = threadIdx.x;
        float bv = sval[t];
        int   bi = sidx[t];
#pragma unroll
        for (int w = 1; w < 16; ++w) {
            float v  = sval[w * 256 + t];
            int   i2 = sidx[w * 256 + t];
            if (v < bv || (v == bv && i2 < bi)) { bv = v; bi = i2; }
        }
        pv[b * 256 + t]  = bv;
        pix[b * 256 + t] = bi - tcbase;   // local target index 0..8191
    }
}

__global__ __launch_bounds__(256) void chamfer_merge(const float* __restrict__ pv,
                                                     const int* __restrict__ pix,
                                                     float* __restrict__ out) {
    int g = blockIdx.x * 256 + threadIdx.x;   // 0..65535
    int dir = g >> 15;
    int w   = g & 32767;
    int n   = w >> 13;
    int v   = w & 8191;
    int qg  = v >> 8;
    int qi  = v & 255;

    int b0 = ((dir * 4 + n) * 32 + qg) * 2;   // nn block id with sh=0
    int i0 = b0 * 256 + qi;
    int i1 = i0 + 256;                         // sh=1 partial

    float v0 = pv[i0], v1 = pv[i1];
    int   j0 = pix[i0], j1 = pix[i1];
    float bv; int bi;
    if (v1 < v0) { bv = v1; bi = j1; }         // ties -> half 0 (smaller idx)
    else         { bv = v0; bi = j0; }

    int o = n * 8192 + qg * 256 + qi;
    int distoff = dir ? 32768 : 0;
    int idxoff  = dir ? 98304 : 65536;
    out[distoff + o] = bv;
    out[idxoff + o]  = (float)bi;
}

extern "C" void kernel_launch(void* const* d_in, const int* in_sizes, int n_in,
                              void* d_out, int out_size, void* d_ws, size_t ws_size,
                              hipStream_t stream) {
    const float* x = (const float*)d_in[0];
    const float* y = (const float*)d_in[1];
    float* ws  = (float*)d_ws;
    float* out = (float*)d_out;

    chamfer_prep<<<256, 256, 0, stream>>>(x, y, ws);
    chamfer_nn<<<512, 1024, 0, stream>>>(ws, ws + OFF_PV, (int*)(ws + OFF_PI));
    chamfer_merge<<<256, 256, 0, stream>>>(ws + OFF_PV, (const int*)(ws + OFF_PI), out);
}

// Round 4
// 111.265 us; speedup vs baseline: 1.2205x; 1.2205x over previous
//
#include <hip/hip_runtime.h>

// Chamfer distance K=1 NN, both directions. N=4, P1=P2=8192, D=3, fp32.
//
// Selection vs reporting split:
//   - Selection key (main loop), per target t and query p:
//       d = fma(a_t, px, s_t); d = fma(b_t, py, d); d = fma(c_t, pz, d)
//     with per-point precomputed (a,b,c,s) = (-2x,-2y,-2z,||p||^2).
//     u = d2 - sp up to ~1ulp reordering; argmin unaffected (runner-up
//     gaps >= 1e-4 >> 1e-7 perturbation). s_t is copied SGPR->VGPR once
//     per pair (shared by 4 queries) so every pk op reads <=1 SGPR.
//   - Reported value (rescan of winning 16-target block): exact reference
//     numerics, bitwise numpy fp32:
//       dot = ((px*qx)+(py*qy))+(pz*qz);  t = fmaf(-2, dot, sp+sq)
//     ascending strict < -> first-occurrence argmin tie-break.
//
// Register discipline (round-3 lesson): __launch_bounds__ min-waves=8 made
// the compiler cap at 32 VGPRs and spill the Q=4 state to scratch (87 MB
// WRITE_SIZE, 80 us). Here: 512-thr blocks, __launch_bounds__(512,4)
// (cap 128), and a lean live set (no scalar px/py/pz copies; sp loaded at
// rescan). Expected ~60-70 VGPR, zero spill, 6-8 waves/SIMD.
//
// Structure:
//   prep : SoA [A|B|C|S] (65536 each) in ws; A=-2x etc, S=((x*x)+(y*y))+(z*z).
//          Queries recover px = -0.5f*A[q] (exact).
//   nn   : 512 blocks x 512 thr = 8 waves. Block = 256 queries (4 per
//          lane) x half target cloud; wave w scans targets
//          [sh*4096 + w*512, +512) via wave-uniform s_load, 16 targets/iter
//          shared by 4 query chains, pm-fold min + min3 tree, winning-iter
//          tracking, exact dwordx4 rescan per query, LDS reduce across
//          8 waves -> per-(block,query) partial. ws footprint = 2 MB.
//   merge: 65536 thr, combine the 2 half-cloud partials per query
//          (strict <: ties keep half 0 = smaller indices), write out.

typedef float v2f __attribute__((ext_vector_type(2)));
typedef float v4f __attribute__((ext_vector_type(4)));

#define NPTS 32768
#define TSEG 512
#define UN 16
#define Q 4

// ws float offsets (total 524288 floats = 2 MB, same as round-0 footprint)
#define OFF_A 0
#define OFF_B 65536
#define OFF_C 131072
#define OFF_S 196608
#define OFF_PV 262144
#define OFF_PI 393216

__device__ __forceinline__ float min3f(float a, float b, float c) {
    float d;
    asm("v_min3_f32 %0, %1, %2, %3" : "=v"(d) : "v"(a), "v"(b), "v"(c));
    return d;
}

__global__ __launch_bounds__(256) void chamfer_prep(const float* __restrict__ x,
                                                    const float* __restrict__ y,
                                                    float* __restrict__ ws) {
#pragma clang fp contract(off)
    int i = blockIdx.x * 256 + threadIdx.x;     // 0..65535
    const float* src = (i < NPTS) ? x : y;
    int j = (i < NPTS) ? i : (i - NPTS);
    float a = src[j * 3 + 0];
    float b = src[j * 3 + 1];
    float c = src[j * 3 + 2];
    ws[OFF_A + i] = -2.0f * a;                  // exact
    ws[OFF_B + i] = -2.0f * b;
    ws[OFF_C + i] = -2.0f * c;
    ws[OFF_S + i] = ((a * a) + (b * b)) + (c * c);  // bitwise numpy order
}

__global__ __launch_bounds__(512, 4) void chamfer_nn(const float* __restrict__ ws,
                                                     float* __restrict__ pv,
                                                     int* __restrict__ pix) {
#pragma clang fp contract(off)
    int b   = blockIdx.x;            // 0..511   (dir<<8 | n<<6 | qg<<1 | sh)
    int dir = b >> 8;                // 0: x->y, 1: y->x
    int r   = b & 255;
    int n   = r >> 6;                // batch 0..3
    int r2  = r & 63;
    int qg  = r2 >> 1;               // query group of 256 (0..31)
    int sh  = r2 & 1;                // target half
    int lane = threadIdx.x & 63;
    int seg  = threadIdx.x >> 6;     // wave id 0..7

    const float* A = ws + OFF_A;
    const float* B = ws + OFF_B;
    const float* C = ws + OFF_C;
    const float* S = ws + OFF_S;

    int qbase  = (dir ? NPTS : 0) + n * 8192 + qg * 256;
    int tcbase = (dir ? 0 : NPTS) + n * 8192;          // target cloud base
    int tbase  = tcbase + sh * 4096 + seg * TSEG;      // this wave's segment

    // per-slot query broadcast pairs (slot q -> query qbase + q*64 + lane);
    // scalar coords recovered later as px2[q].x (no extra registers).
    v2f px2[Q], py2[Q], pz2[Q];
#pragma unroll
    for (int q = 0; q < Q; ++q) {
        int qi = qbase + q * 64 + lane;
        float ax = -0.5f * A[qi];    // exact recovery of original coords
        float ay = -0.5f * B[qi];
        float az = -0.5f * C[qi];
        px2[q].x = ax; px2[q].y = ax;
        py2[q].x = ay; py2[q].y = ay;
        pz2[q].x = az; pz2[q].y = az;
    }

    const v2f* A2 = (const v2f*)A;
    const v2f* B2 = (const v2f*)B;
    const v2f* C2 = (const v2f*)C;
    const v2f* S2 = (const v2f*)S;

    float best[Q];
    int   bblk[Q];
#pragma unroll
    for (int q = 0; q < Q; ++q) { best[q] = __builtin_inff(); bblk[q] = 0; }

    for (int blk = 0; blk < TSEG / UN; ++blk) {
        int t0 = __builtin_amdgcn_readfirstlane(tbase + blk * UN);
        int p0 = t0 >> 1;                               // v2f pair index
        float pm[Q][4];                                 // 4 running mins/query
#pragma unroll
        for (int i = 0; i < UN / 2; ++i) {
            v2f av = A2[p0 + i];
            v2f bv = B2[p0 + i];
            v2f cv = C2[p0 + i];
            v2f sv = S2[p0 + i];    // -> 1 VGPR copy, shared by 4 queries
#pragma unroll
            for (int q = 0; q < Q; ++q) {
                // 3 pk ops, each with exactly 1 SGPR source
                v2f d = __builtin_elementwise_fma(av, px2[q], sv);
                d = __builtin_elementwise_fma(bv, py2[q], d);
                d = __builtin_elementwise_fma(cv, pz2[q], d);
                float f = fminf(d.x, d.y);
                if ((i & 1) == 0) pm[q][i >> 1] = f;
                else              pm[q][i >> 1] = fminf(pm[q][i >> 1], f);
            }
        }
#pragma unroll
        for (int q = 0; q < Q; ++q) {
            float m = fminf(min3f(pm[q][0], pm[q][1], pm[q][2]), pm[q][3]);
            if (m < best[q]) { best[q] = m; bblk[q] = blk; }  // strict <
        }
    }

    // Exact rescan of each winning 16-target block with reference numerics.
    // Ascending + strict < -> smallest index on exact-t ties (argmin).
    const v4f* A4 = (const v4f*)A;
    const v4f* B4 = (const v4f*)B;
    const v4f* C4 = (const v4f*)C;
    const v4f* S4 = (const v4f*)S;

    __shared__ float sval[2048];
    __shared__ int   sidx[2048];

#pragma unroll
    for (int q = 0; q < Q; ++q) {
        int qi = qbase + q * 64 + lane;
        float sp = S[qi];
        float px = px2[q].x, py = py2[q].x, pz = pz2[q].x;
        int t0v = tbase + bblk[q] * UN;                // 16-aligned
        int q4 = t0v >> 2;
        float bt = __builtin_inff();
        int bi = t0v;
#pragma unroll
        for (int c = 0; c < 4; ++c) {
            v4f qa = A4[q4 + c], qb = B4[q4 + c], qc = C4[q4 + c], qs = S4[q4 + c];
#pragma unroll
            for (int j = 0; j < 4; ++j) {
                float qx = -0.5f * qa[j], qy = -0.5f * qb[j], qz = -0.5f * qc[j];
                float dot = ((px * qx) + (py * qy)) + (pz * qz);
                float t   = fmaf(-2.0f, dot, sp + qs[j]);
                if (t < bt) { bt = t; bi = t0v + c * 4 + j; }
            }
        }
        sval[seg * 256 + q * 64 + lane] = bt;
        sidx[seg * 256 + q * 64 + lane] = bi;
    }
    __syncthreads();

    // cross-wave reduction: 8 waves x 256 queries. seg order ascending
    // preserves smallest-index tie-break (lower seg = lower target index).
    if (threadIdx.x < 256) {
        int t = threadIdx.x;
        float bv = sval[t];
        int   bi = sidx[t];
#pragma unroll
        for (int w = 1; w < 8; ++w) {
            float v  = sval[w * 256 + t];
            int   i2 = sidx[w * 256 + t];
            if (v < bv || (v == bv && i2 < bi)) { bv = v; bi = i2; }
        }
        pv[b * 256 + t]  = bv;
        pix[b * 256 + t] = bi - tcbase;   // local target index 0..8191
    }
}

__global__ __launch_bounds__(256) void chamfer_merge(const float* __restrict__ pv,
                                                     const int* __restrict__ pix,
                                                     float* __restrict__ out) {
    int g = blockIdx.x * 256 + threadIdx.x;   // 0..65535
    int dir = g >> 15;
    int w   = g & 32767;
    int n   = w >> 13;
    int v   = w & 8191;
    int qg  = v >> 8;
    int qi  = v & 255;

    int b0 = ((dir * 4 + n) * 32 + qg) * 2;   // nn block id with sh=0
    int i0 = b0 * 256 + qi;
    int i1 = i0 + 256;                         // sh=1 partial

    float v0 = pv[i0], v1 = pv[i1];
    int   j0 = pix[i0], j1 = pix[i1];
    float bv; int bi;
    if (v1 < v0) { bv = v1; bi = j1; }         // ties -> half 0 (smaller idx)
    else         { bv = v0; bi = j0; }

    int o = n * 8192 + qg * 256 + qi;
    int distoff = dir ? 32768 : 0;
    int idxoff  = dir ? 98304 : 65536;
    out[distoff + o] = bv;
    out[idxoff + o]  = (float)bi;
}

extern "C" void kernel_launch(void* const* d_in, const int* in_sizes, int n_in,
                              void* d_out, int out_size, void* d_ws, size_t ws_size,
                              hipStream_t stream) {
    const float* x = (const float*)d_in[0];
    const float* y = (const float*)d_in[1];
    float* ws  = (float*)d_ws;
    float* out = (float*)d_out;

    chamfer_prep<<<256, 256, 0, stream>>>(x, y, ws);
    chamfer_nn<<<512, 512, 0, stream>>>(ws, ws + OFF_PV, (int*)(ws + OFF_PI));
    chamfer_merge<<<256, 256, 0, stream>>>(ws + OFF_PV, (const int*)(ws + OFF_PI), out);
}